// Round 6
// baseline (94.560 us; speedup 1.0000x reference)
//
#include <hip/hip_runtime.h>
#include <hip/hip_bf16.h>

typedef __bf16 bf16;
typedef __bf16 bf16x8 __attribute__((ext_vector_type(8)));
typedef __bf16 bf16x4 __attribute__((ext_vector_type(4)));
typedef float  f32x4  __attribute__((ext_vector_type(4)));

#define KDIM 512
#define MDIM 64
#define TDIM 4096
#define BN   128
#define NTILE (TDIM / BN)   // 32 tiles per batch
#define NKT  (KDIM / 32)    // 16 k-steps of 32

// LDS: text [64][512] bf16, swizzled (row stride 1024B) = 65536 B; invT 256 B
#define TX_OFF   0
#define INVT_OFF 65536
#define LDS_BYTES 65792

// ---- audio B-fragment load/consume macros: all register indices static ----

#define LOADSET(S0, S1, S2, S3, K0) do {                                      \
    S0 = *reinterpret_cast<const f32x4*>(aP0 + (K0));                         \
    S1 = *reinterpret_cast<const f32x4*>(aP0 + (K0) + 4);                     \
    S2 = *reinterpret_cast<const f32x4*>(aP1 + (K0));                         \
    S3 = *reinterpret_cast<const f32x4*>(aP1 + (K0) + 4);                     \
} while (0)

#define CONSUME(S0, S1, S2, S3, KT_IDX) do {                                  \
    ssA0 += S0.x*S0.x + S0.y*S0.y + S0.z*S0.z + S0.w*S0.w                     \
          + S1.x*S1.x + S1.y*S1.y + S1.z*S1.z + S1.w*S1.w;                    \
    ssA1 += S2.x*S2.x + S2.y*S2.y + S2.z*S2.z + S2.w*S2.w                     \
          + S3.x*S3.x + S3.y*S3.y + S3.z*S3.z + S3.w*S3.w;                    \
    bf16x8 bf0, bf1;                                                          \
    bf0[0]=(bf16)S0.x; bf0[1]=(bf16)S0.y; bf0[2]=(bf16)S0.z; bf0[3]=(bf16)S0.w;\
    bf0[4]=(bf16)S1.x; bf0[5]=(bf16)S1.y; bf0[6]=(bf16)S1.z; bf0[7]=(bf16)S1.w;\
    bf1[0]=(bf16)S2.x; bf1[1]=(bf16)S2.y; bf1[2]=(bf16)S2.z; bf1[3]=(bf16)S2.w;\
    bf1[4]=(bf16)S3.x; bf1[5]=(bf16)S3.y; bf1[6]=(bf16)S3.z; bf1[7]=(bf16)S3.w;\
    /* HAZARD GUARD: VALU write -> opaque-asm MFMA read needs SW wait      */ \
    /* states; compiler can't see the MFMA inside asm (R4->R5 confirmed). */ \
    asm volatile("s_nop 7" : : "v"(bf0), "v"(bf1));                           \
    const int kbyte = (KT_IDX) * 64 + kgrp * 16;                              \
    bf16x8 afrag[4];                                                          \
    _Pragma("unroll")                                                         \
    for (int mi = 0; mi < 4; ++mi) {                                          \
        const int row = mi * 16 + frow;                                       \
        afrag[mi] = *reinterpret_cast<const bf16x8*>(                         \
            lds + TX_OFF + row * 1024 + (kbyte ^ ((row & 7) << 4)));          \
    }                                                                         \
    _Pragma("unroll")                                                         \
    for (int mi = 0; mi < 4; ++mi) {                                          \
        asm volatile("v_mfma_f32_16x16x32_bf16 %0, %1, %2, %0"                \
                     : "+v"(acc[mi][0]) : "v"(afrag[mi]), "v"(bf0));          \
        asm volatile("v_mfma_f32_16x16x32_bf16 %0, %1, %2, %0"                \
                     : "+v"(acc[mi][1]) : "v"(afrag[mi]), "v"(bf1));          \
    }                                                                         \
} while (0)

__global__ __launch_bounds__(256, 2)
void expnegl2_fused_kernel(const float* __restrict__ audio,
                           const float* __restrict__ text,
                           float* __restrict__ out)
{
    __shared__ __attribute__((aligned(16))) unsigned char lds[LDS_BYTES];

    const int tid  = threadIdx.x;

    // XCD swizzle: each XCD owns 4 contiguous batches -> text L2-resident
    const int linear = blockIdx.x;
    const int cpx    = gridDim.x >> 3;
    const int wg     = (linear & 7) * cpx + (linear >> 3);
    const int b      = wg / NTILE;
    const int t0     = (wg % NTILE) * BN;

    const int lane = tid & 63;
    const int wave = tid >> 6;
    const int frow = lane & 15;  // MFMA row/col within 16
    const int kgrp = lane >> 4;  // MFMA k-octet selector

    const float* tBase = text + (size_t)b * MDIM * KDIM;

    // ---------------- Phase 1: text -> bf16 LDS (whole K), ssT, invT -------
    {
        const int c4 = tid & 15;   // 16B column chunk
        const int r0 = tid >> 4;   // base row 0..15
        #pragma unroll
        for (int j = 0; j < 4; ++j) {
            const int row = j * 16 + r0;
            const float* tr = tBase + (size_t)row * KDIM;
            float ss = 0.f;
            #pragma unroll
            for (int p = 0; p < 8; ++p) {
                f32x4 v = *reinterpret_cast<const f32x4*>(tr + p * 64 + c4 * 4);
                ss += v.x * v.x + v.y * v.y + v.z * v.z + v.w * v.w;
                bf16x4 q = { (bf16)v.x, (bf16)v.y, (bf16)v.z, (bf16)v.w };
                const int off = TX_OFF + row * 1024 +
                                ((p * 128 + c4 * 8) ^ ((row & 7) << 4));
                *reinterpret_cast<unsigned long long*>(lds + off) =
                    __builtin_bit_cast(unsigned long long, q);
            }
            ss += __shfl_xor(ss, 1); ss += __shfl_xor(ss, 2);
            ss += __shfl_xor(ss, 4); ss += __shfl_xor(ss, 8);
            if (c4 == 0)
                reinterpret_cast<float*>(lds + INVT_OFF)[row] =
                    1.f / fmaxf(sqrtf(ss), 1e-12f);
        }
    }
    __syncthreads();   // the ONLY barrier

    // ---------------- Phase 2: barrier-free K-loop, 4-deep prefetch --------
    // MLP: a CU needs ~9.2KB in flight to hide ~375ns at 24.6 GB/s; with 8
    // waves that's ~9 dwordx4/wave outstanding. 4-deep x 4 loads gives
    // ~12-16 steady-state (2-deep's ~6 was the R5 limiter).
    const int arow0 = t0 + wave * 32 + frow;
    const float* aP0 = audio + ((size_t)b * TDIM + arow0) * KDIM + kgrp * 8;
    const float* aP1 = aP0 + 16 * KDIM;

    f32x4 acc[4][2];
    #pragma unroll
    for (int i = 0; i < 4; ++i) {
        acc[i][0] = (f32x4){0.f, 0.f, 0.f, 0.f};
        acc[i][1] = (f32x4){0.f, 0.f, 0.f, 0.f};
    }
    float ssA0 = 0.f, ssA1 = 0.f;

    f32x4 s0a, s0b, s0c, s0d, s1a, s1b, s1c, s1d;
    f32x4 s2a, s2b, s2c, s2d, s3a, s3b, s3c, s3d;

    LOADSET(s0a, s0b, s0c, s0d, 0);
    LOADSET(s1a, s1b, s1c, s1d, 32);
    LOADSET(s2a, s2b, s2c, s2d, 64);
    LOADSET(s3a, s3b, s3c, s3d, 96);

    #pragma unroll
    for (int kt = 0; kt < NKT; kt += 4) {
        CONSUME(s0a, s0b, s0c, s0d, kt);
        if (kt + 4 < NKT) LOADSET(s0a, s0b, s0c, s0d, (kt + 4) * 32);
        CONSUME(s1a, s1b, s1c, s1d, kt + 1);
        if (kt + 5 < NKT) LOADSET(s1a, s1b, s1c, s1d, (kt + 5) * 32);
        CONSUME(s2a, s2b, s2c, s2d, kt + 2);
        if (kt + 6 < NKT) LOADSET(s2a, s2b, s2c, s2d, (kt + 6) * 32);
        CONSUME(s3a, s3b, s3c, s3d, kt + 3);
        if (kt + 7 < NKT) LOADSET(s3a, s3b, s3c, s3d, (kt + 7) * 32);
    }

    // HAZARD GUARD: opaque-asm MFMA write -> VALU read of acc.
    asm volatile("s_nop 7" : : "v"(acc[0][0]), "v"(acc[3][1]));
    asm volatile("s_nop 7" : : "v"(acc[1][0]), "v"(acc[2][1]));

    // audio inv-norms: reduce across the 4 k-octet lanes sharing a row;
    // every lane ends up holding exactly the invA its epilogue column needs.
    ssA0 += __shfl_xor(ssA0, 16); ssA0 += __shfl_xor(ssA0, 32);
    ssA1 += __shfl_xor(ssA1, 16); ssA1 += __shfl_xor(ssA1, 32);
    const float iA0 = 1.f / fmaxf(sqrtf(ssA0), 1e-12f);
    const float iA1 = 1.f / fmaxf(sqrtf(ssA1), 1e-12f);

    // ---------------- Epilogue --------------------------------------------
    // C/D layout (16x16x32): col = lane&15, row = (lane>>4)*4 + j  [m89]
    const float* invT = reinterpret_cast<const float*>(lds + INVT_OFF);
    float* obase = out + (size_t)b * MDIM * TDIM + t0;
    #pragma unroll
    for (int ni = 0; ni < 2; ++ni) {
        const int cl = wave * 32 + ni * 16 + frow;
        const float iA = ni ? iA1 : iA0;
        #pragma unroll
        for (int mi = 0; mi < 4; ++mi) {
            #pragma unroll
            for (int j = 0; j < 4; ++j) {
                const int m = mi * 16 + kgrp * 4 + j;
                const float dotn = acc[mi][ni][j] * invT[m] * iA;
                const float d2 = fmaxf(2.f - 2.f * dotn, 1e-12f);
                obase[(size_t)m * TDIM + cl] = __expf(-sqrtf(d2));
            }
        }
    }
}

extern "C" void kernel_launch(void* const* d_in, const int* in_sizes, int n_in,
                              void* d_out, int out_size, void* d_ws, size_t ws_size,
                              hipStream_t stream) {
    const float* audio = (const float*)d_in[0];
    const float* text  = (const float*)d_in[1];
    float* out = (float*)d_out;

    const int B = in_sizes[0] / (TDIM * KDIM);   // 32
    dim3 grid(B * NTILE);                        // 1024, %8==0
    expnegl2_fused_kernel<<<grid, 256, 0, stream>>>(audio, text, out);
}

// Round 7
// 57.951 us; speedup vs baseline: 1.6317x; 1.6317x over previous
//
#include <hip/hip_runtime.h>
#include <hip/hip_bf16.h>

typedef __bf16 bf16;
typedef __bf16 bf16x8 __attribute__((ext_vector_type(8)));
typedef __bf16 bf16x4 __attribute__((ext_vector_type(4)));
typedef float  f32x4  __attribute__((ext_vector_type(4)));

#define KDIM 512
#define MDIM 64
#define TDIM 4096
#define BN   128
#define BK   64
#define NTILE (TDIM / BN)   // 32 tiles per batch
#define KITER (KDIM / BK)   // 8

// LDS byte layout
#define SA_OFF   0        // text tile  [64][64]  bf16, swizzled: 8192 B
#define SB_OFF   8192     // audio tile [128][64] bf16, swizzled: 16384 B
#define INVT_OFF 24576    // 64 floats
#define INVA_OFF 24832    // 128 floats
#define LDS_BYTES 25344

// ---- macros: every register-array index compile-time static (rule #20) ----

#define LOAD_TILE(PT, PA, K0) do {                                            \
    _Pragma("unroll")                                                         \
    for (int j = 0; j < 4; ++j)                                               \
        PT[j] = *reinterpret_cast<const f32x4*>(                              \
            tBase + (size_t)(j * 16 + r0) * KDIM + (K0) + c4 * 4);            \
    _Pragma("unroll")                                                         \
    for (int j = 0; j < 8; ++j)                                               \
        PA[j] = *reinterpret_cast<const f32x4*>(                              \
            aBase + (size_t)(j * 16 + r0) * KDIM + (K0) + c4 * 4);            \
} while (0)

#define STORE_TILE(PT, PA) do {                                               \
    _Pragma("unroll")                                                         \
    for (int j = 0; j < 4; ++j) {                                             \
        f32x4 v = PT[j];                                                      \
        ssT[j] += v.x * v.x + v.y * v.y + v.z * v.z + v.w * v.w;              \
        bf16x4 q = { (bf16)v.x, (bf16)v.y, (bf16)v.z, (bf16)v.w };            \
        const int row = j * 16 + r0;                                          \
        const int off = SA_OFF + row * 128 + ((c4 * 8) ^ ((row & 7) << 4));   \
        *reinterpret_cast<unsigned long long*>(lds + off) =                   \
            __builtin_bit_cast(unsigned long long, q);                        \
    }                                                                         \
    _Pragma("unroll")                                                         \
    for (int j = 0; j < 8; ++j) {                                             \
        f32x4 v = PA[j];                                                      \
        ssA[j] += v.x * v.x + v.y * v.y + v.z * v.z + v.w * v.w;              \
        bf16x4 q = { (bf16)v.x, (bf16)v.y, (bf16)v.z, (bf16)v.w };            \
        const int row = j * 16 + r0;                                          \
        const int off = SB_OFF + row * 128 + ((c4 * 8) ^ ((row & 7) << 4));   \
        *reinterpret_cast<unsigned long long*>(lds + off) =                   \
            __builtin_bit_cast(unsigned long long, q);                        \
    }                                                                         \
} while (0)

#define MFMA_PHASE() do {                                                     \
    _Pragma("unroll")                                                         \
    for (int kk = 0; kk < 2; ++kk) {                                          \
        const int kbyte = kk * 64 + kgrp * 16;                                \
        bf16x8 afrag[4], bfrag[2];                                            \
        _Pragma("unroll")                                                     \
        for (int mi = 0; mi < 4; ++mi) {                                      \
            const int row = mi * 16 + frow;                                   \
            afrag[mi] = *reinterpret_cast<const bf16x8*>(                     \
                lds + SA_OFF + row * 128 + (kbyte ^ ((row & 7) << 4)));       \
        }                                                                     \
        _Pragma("unroll")                                                     \
        for (int ni = 0; ni < 2; ++ni) {                                      \
            const int trow = wave * 32 + ni * 16 + frow;                      \
            bfrag[ni] = *reinterpret_cast<const bf16x8*>(                     \
                lds + SB_OFF + trow * 128 + (kbyte ^ ((trow & 7) << 4)));     \
        }                                                                     \
        _Pragma("unroll")                                                     \
        for (int mi = 0; mi < 4; ++mi)                                        \
            _Pragma("unroll")                                                 \
            for (int ni = 0; ni < 2; ++ni)                                    \
                asm volatile("v_mfma_f32_16x16x32_bf16 %0, %1, %2, %0"        \
                             : "+v"(acc[mi][ni])                              \
                             : "v"(afrag[mi]), "v"(bfrag[ni]));               \
    }                                                                         \
} while (0)

// T4 barrier pair: ds-visibility wait ONLY (no vmcnt drain!), raw s_barrier.
// __syncthreads() would emit s_waitcnt vmcnt(0) and kill the cross-barrier
// prefetch (the m97-ceiling mechanism). sched_barrier(0) pins so the
// scheduler can't float memory ops across the barrier.
#define RAW_BARRIER() do {                                                    \
    __builtin_amdgcn_sched_barrier(0);                                        \
    asm volatile("s_waitcnt lgkmcnt(0)" ::: "memory");                        \
    __builtin_amdgcn_s_barrier();                                             \
    __builtin_amdgcn_sched_barrier(0);                                        \
} while (0)

__global__ __launch_bounds__(256, 2)
void expnegl2_fused_kernel(const float* __restrict__ audio,
                           const float* __restrict__ text,
                           float* __restrict__ out)
{
    __shared__ __attribute__((aligned(16))) unsigned char lds[LDS_BYTES];

    const int tid  = threadIdx.x;

    // XCD swizzle: each XCD owns 4 contiguous batches (text L2 locality)
    const int linear = blockIdx.x;
    const int cpx    = gridDim.x >> 3;
    const int wg     = (linear & 7) * cpx + (linear >> 3);
    const int b      = wg / NTILE;
    const int t0     = (wg % NTILE) * BN;

    const int c4   = tid & 15;
    const int r0   = tid >> 4;
    const int lane = tid & 63;
    const int wave = tid >> 6;

    const float* aBase = audio + ((size_t)b * TDIM + t0) * KDIM;
    const float* tBase = text  + (size_t)b * MDIM * KDIM;

    f32x4 acc[4][2];
    #pragma unroll
    for (int i = 0; i < 4; ++i)
        #pragma unroll
        for (int j = 0; j < 2; ++j)
            acc[i][j] = (f32x4){0.f, 0.f, 0.f, 0.f};

    float ssA[8], ssT[4];
    #pragma unroll
    for (int j = 0; j < 8; ++j) ssA[j] = 0.f;
    #pragma unroll
    for (int j = 0; j < 4; ++j) ssT[j] = 0.f;

    const int frow = lane & 15;
    const int kgrp = lane >> 4;

    // 2-deep register prefetch. With RAW barriers the ~24 in-flight loads
    // SURVIVE the barrier; the wait at the next STORE_TILE is a counted
    // vmcnt(12) issued ~2 phases (>=800cyc) after the loads -> near-zero stall.
    f32x4 pT0[4], pA0[8], pT1[4], pA1[8];

    LOAD_TILE(pT0, pA0, 0);
    LOAD_TILE(pT1, pA1, BK);

    #pragma unroll
    for (int ki = 0; ki < KITER; ki += 2) {
        // ---- even sub-iter: consume set0 (tile ki), refill with ki+2 ----
        STORE_TILE(pT0, pA0);                    // compiler: counted vmcnt on set0
        if (ki + 2 < KITER) LOAD_TILE(pT0, pA0, (ki + 2) * BK);
        RAW_BARRIER();                           // tile ki visible; loads stay in flight
        MFMA_PHASE();
        RAW_BARRIER();                           // all ds_reads done -> LDS reusable

        // ---- odd sub-iter: consume set1 (tile ki+1), refill with ki+3 ----
        STORE_TILE(pT1, pA1);
        if (ki + 3 < KITER) LOAD_TILE(pT1, pA1, (ki + 3) * BK);
        RAW_BARRIER();
        MFMA_PHASE();
        RAW_BARRIER();
    }

    // ---- reduce sum-of-squares across the 16 lanes sharing a row ----
    #pragma unroll
    for (int j = 0; j < 4; ++j) {
        float s = ssT[j];
        s += __shfl_xor(s, 1); s += __shfl_xor(s, 2);
        s += __shfl_xor(s, 4); s += __shfl_xor(s, 8);
        ssT[j] = s;
    }
    #pragma unroll
    for (int j = 0; j < 8; ++j) {
        float s = ssA[j];
        s += __shfl_xor(s, 1); s += __shfl_xor(s, 2);
        s += __shfl_xor(s, 4); s += __shfl_xor(s, 8);
        ssA[j] = s;
    }
    float* invT = reinterpret_cast<float*>(lds + INVT_OFF);
    float* invA = reinterpret_cast<float*>(lds + INVA_OFF);
    if (c4 == 0) {
        #pragma unroll
        for (int j = 0; j < 4; ++j)
            invT[j * 16 + r0] = 1.f / fmaxf(sqrtf(ssT[j]), 1e-12f);
        #pragma unroll
        for (int j = 0; j < 8; ++j)
            invA[j * 16 + r0] = 1.f / fmaxf(sqrtf(ssA[j]), 1e-12f);
    }
    __syncthreads();   // one-time full drain: harmless here

    // ---- epilogue: C/D layout col = lane&15, row = (lane>>4)*4 + j [m89] ----
    float* obase = out + (size_t)b * MDIM * TDIM + t0;
    #pragma unroll
    for (int ni = 0; ni < 2; ++ni) {
        const int cl = wave * 32 + ni * 16 + frow;
        const float iA = invA[cl];
        #pragma unroll
        for (int mi = 0; mi < 4; ++mi) {
            #pragma unroll
            for (int j = 0; j < 4; ++j) {
                const int m = mi * 16 + kgrp * 4 + j;
                const float dotn = acc[mi][ni][j] * invT[m] * iA;
                const float d2 = fmaxf(2.f - 2.f * dotn, 1e-12f);
                obase[(size_t)m * TDIM + cl] = __expf(-sqrtf(d2));
            }
        }
    }
}

extern "C" void kernel_launch(void* const* d_in, const int* in_sizes, int n_in,
                              void* d_out, int out_size, void* d_ws, size_t ws_size,
                              hipStream_t stream) {
    const float* audio = (const float*)d_in[0];
    const float* text  = (const float*)d_in[1];
    float* out = (float*)d_out;

    const int B = in_sizes[0] / (TDIM * KDIM);   // 32
    dim3 grid(B * NTILE);                        // 1024, %8==0
    expnegl2_fused_kernel<<<grid, 256, 0, stream>>>(audio, text, out);
}